// Round 11
// baseline (357.463 us; speedup 1.0000x reference)
//
#include <hip/hip_runtime.h>

// SSP transform: out[b,n] = 1/513 + sum_k A[b,k]*Bt[n,k]
//   A[b,j]=cos(x_b*phi_j), A[b,256+j]=sin(x_b*phi_j)
//   Bt[n,j]=(2/513)cos(2pi(j+1)n/513), Bt[n,256+j]=-(2/513)sin(2pi(j+1)n/513)
// bf16 MFMA GEMM M=131072 N=513(pad 544) K=512.
// R10 post-mortem: timed graph = poison fill (~197us, 1.076GB) + genB + ssp_main
//   (~153us). R2's store/vmcnt fixes were ~neutral vs R1's scalar stores +
//   full drain => NOT store-bound, NOT drain-bound. Throughput model says
//   ~60-110us => latency-bound at 2 waves/SIMD (VGPR ~200).
// R11: occupancy experiment. 16 rows/wave (512-thr blocks, 8 waves, BM=128):
//   afrag 128->64 VGPR, launch_bounds(512,4) forces <=128 VGPR => 4 waves/SIMD,
//   16 waves/CU. LDS traffic doubles (B-frag reuse 2->1). Discriminating test:
//   latency-bound -> dur ~300-315; LDS-throughput-bound -> dur ~385-400.

#define DIMN 513
#define KDIM 512
#define NPAD 544
#define NPAIRS 17
#define BM 128
#define INV_N (1.0f / 513.0f)

typedef __attribute__((ext_vector_type(8))) short short8;   // 8 bf16
typedef __attribute__((ext_vector_type(4))) float f32x4;
typedef __attribute__((ext_vector_type(4))) float f4;
typedef __attribute__((ext_vector_type(4), aligned(4))) float f4u; // unaligned-ok store

__device__ __forceinline__ short bf16r(float f) {
  unsigned u = __float_as_uint(f);
  u += 0x7FFFu + ((u >> 16) & 1u);
  return (short)(u >> 16);
}

// ---------------- genB: constant matrix, swizzled for LDS staging --------------
// Logical (n,k) -> within-32-row-chunk byte w = (n&31)*1024 + k*2,
// stored at (n>>5)*32768 + (w ^ ((n&7)<<4)). Main kernel copies chunks linearly
// to LDS (global_load_lds) and reads with the same XOR -> conflict-free b128.
__global__ void ssp_genB(unsigned short* __restrict__ bt) {
  int idx = blockIdx.x * 256 + threadIdx.x;   // 544*512 = 278528
  int n = idx >> 9;
  int k = idx & 511;
  int j = k & 255;
  unsigned prod = (unsigned)(j + 1) * (unsigned)n;
  unsigned m = prod % 513u;                   // exact angle reduction
  float ang = (float)m * (6.283185307179586f / 513.0f);
  float s, c;
  __sincosf(ang, &s, &c);
  float v = (k < 256) ? c * (2.0f / 513.0f) : -(s * (2.0f / 513.0f));
  unsigned chunk = (unsigned)n >> 5;
  unsigned w = ((unsigned)(n & 31) << 10) + ((unsigned)k << 1);
  unsigned phys = (chunk << 15) + (w ^ ((unsigned)(n & 7) << 4));
  bt[phys >> 1] = (unsigned short)bf16r(v);
}

// ---------------- main fused kernel -------------------------------------------
// 512 threads = 8 waves, wave w owns rows [blk*128 + w*16, +16).
__global__ __launch_bounds__(512, 4) void ssp_main(
    const float* __restrict__ x, const float* __restrict__ phis,
    const unsigned short* __restrict__ bt, float* __restrict__ out) {
  __shared__ __align__(16) unsigned char lds[65536];   // 2 x 32KB Bt tiles
  const int tid = threadIdx.x;
  const int w = tid >> 6;          // wave 0..7
  const int lane = tid & 63;
  const int r = lane & 15;
  const int q = lane >> 4;
  const long rowW = (long)blockIdx.x * BM + w * 16;

  const unsigned char* btb = (const unsigned char*)bt;

  // ---- issue tile-0 prefetch first; latency hides under sincos ----
  // 512 threads x 16B x 4 rounds = 32KB. Per wave: base w*1024 + i*8192.
  {
#pragma unroll
    for (int i = 0; i < 4; ++i)
      __builtin_amdgcn_global_load_lds(
          (const __attribute__((address_space(1))) unsigned int*)
              (btb + w * 1024 + i * 8192 + lane * 16),
          (__attribute__((address_space(3))) unsigned int*)
              (&lds[w * 1024 + i * 8192]),
          16, 0, 0);
  }

  // ---- Phase 1: A fragments in registers (16 rows per wave) ----
  // afrag[t] elem e = A[rowW + r][k = 32t + 8q + e] (bf16); t<8 cos, t>=8 sin
  short8 afrag[16];
  const float x0 = x[rowW + r];
#pragma unroll
  for (int u = 0; u < 8; ++u) {
    const f4* pp4 = (const f4*)(phis + 32 * u + 8 * q);
    f4 plo = pp4[0];
    f4 phi4 = pp4[1];
#pragma unroll
    for (int e = 0; e < 8; ++e) {
      float ph = (e < 4) ? plo[e] : phi4[e - 4];
      float s0, c0;
      __sincosf(x0 * ph, &s0, &c0);
      afrag[u][e]     = bf16r(c0);
      afrag[u + 8][e] = bf16r(s0);
    }
  }

  // prologue drain: tile-0 (and x/phis) landed, everyone synced
  asm volatile("s_waitcnt vmcnt(0) lgkmcnt(0)" ::: "memory");
  __builtin_amdgcn_s_barrier();

  // swizzled ds_read base offsets (same proven addressing as R2)
  const int sw  = (r & 7) << 4;
  const int be0 = (r << 10)        + ((q << 4) ^ sw);
  const int bo0 = (r << 10)        + ((64 | (q << 4)) ^ sw);
  const int be1 = ((16 + r) << 10) + ((q << 4) ^ sw);
  const int bo1 = ((16 + r) << 10) + ((64 | (q << 4)) ^ sw);

  float* const o0 = out + (rowW + r) * DIMN;   // this lane's batch row

  for (int p = 0; p < NPAIRS; ++p) {
    const int buf = (p & 1) * 32768;

    // (A) prefetch next tile (4 vmem loads)
    if (p + 1 < NPAIRS) {
      const unsigned char* srcb = btb + (p + 1) * 32768;
      const int dbuf = ((p + 1) & 1) * 32768;
#pragma unroll
      for (int i = 0; i < 4; ++i)
        __builtin_amdgcn_global_load_lds(
            (const __attribute__((address_space(1))) unsigned int*)
                (srcb + w * 1024 + i * 8192 + lane * 16),
            (__attribute__((address_space(3))) unsigned int*)
                (&lds[dbuf + w * 1024 + i * 8192]),
            16, 0, 0);
    }
    __builtin_amdgcn_sched_barrier(0);

    // (B) K loop: 16 k-steps; operand-swapped MFMA -> D[col=batch,row=n]
    f32x4 acc0 = {0.f, 0.f, 0.f, 0.f};
    f32x4 acc1 = {0.f, 0.f, 0.f, 0.f};
#pragma unroll
    for (int t = 0; t < 16; ++t) {
      const int o0b = buf + ((t & 1) ? bo0 : be0) + (t >> 1) * 128;
      const int o1b = buf + ((t & 1) ? bo1 : be1) + (t >> 1) * 128;
      short8 b0 = *(const short8*)&lds[o0b];
      short8 b1 = *(const short8*)&lds[o1b];
      acc0 = __builtin_amdgcn_mfma_f32_16x16x32_bf16(b0, afrag[t], acc0, 0, 0, 0);
      acc1 = __builtin_amdgcn_mfma_f32_16x16x32_bf16(b1, afrag[t], acc1, 0, 0, 0);
    }

    // (C) epilogue: lane holds n = p*32 + (0|16) + 4q + rr for batch col r
    const int nb = p * 32 + 4 * q;
    if (p < 16) {
      *(f4u*)(o0 + nb)      = acc0 + INV_N;
      *(f4u*)(o0 + nb + 16) = acc1 + INV_N;
    } else {
      // n range 512..543; only n==512 valid (q==0, reg 0 of low tile)
      if (q == 0) o0[512] = acc0[0] + INV_N;
    }
    __builtin_amdgcn_sched_barrier(0);

    // (D) counted drain: 2 newest vmem ops are this iter's stores; anything
    // older (prev stores + the 4 prefetch loads) is forced complete.
    asm volatile("s_waitcnt vmcnt(2)" ::: "memory");
    // (E) all waves' prefetches landed; buf fully consumed -> safe to swap
    __builtin_amdgcn_s_barrier();
  }
}

extern "C" void kernel_launch(void* const* d_in, const int* in_sizes, int n_in,
                              void* d_out, int out_size, void* d_ws, size_t ws_size,
                              hipStream_t stream) {
  const float* x = (const float*)d_in[0];
  const float* phis = (const float*)d_in[1];
  float* out = (float*)d_out;
  unsigned short* bt = (unsigned short*)d_ws;   // 544*512 bf16 = 557056 B

  ssp_genB<<<dim3(NPAD * KDIM / 256), dim3(256), 0, stream>>>(bt);
  ssp_main<<<dim3(131072 / BM), dim3(512), 0, stream>>>(x, phis, bt, out);
}